// Round 1
// baseline (8028.394 us; speedup 1.0000x reference)
//
#include <hip/hip_runtime.h>

typedef _Float16 f16;
typedef _Float16 f16x8 __attribute__((ext_vector_type(8)));
typedef float f32x4 __attribute__((ext_vector_type(4)));

// dims
#define BB 16
#define TT 128
#define VV 32000
#define EE 400
#define HH 1150
#define MM 2048   // T*B rows

__device__ __forceinline__ float sigm(float x){ return 1.f/(1.f + __expf(-x)); }

// ---------------- conversion kernels ----------------

// emb (V,400) f32 -> emb_bf (V,416) f16, zero-padded K
__global__ void conv_emb(const float* __restrict__ src, f16* __restrict__ dst){
    int v = blockIdx.y;
    int k = blockIdx.x*256 + threadIdx.x;
    if (k >= 416) return;
    float val = (k < EE) ? src[v*EE + k] : 0.f;
    dst[v*416 + k] = (f16)val;
}

// xs0 (2048,416) f16: row m=t*16+b  <- emb[x[b,t]]
__global__ void embed_gather(const float* __restrict__ emb, const int* __restrict__ x,
                             f16* __restrict__ dst){
    int m = blockIdx.y;            // t*16+b
    int k = blockIdx.x*256 + threadIdx.x;
    if (k >= 416) return;
    int t = m >> 4, b = m & 15;
    int row = x[b*TT + t];
    float val = (k < EE) ? emb[row*EE + k] : 0.f;
    dst[m*416 + k] = (f16)val;
}

// W (4*Hout, Ksrc) f32 -> dst (Np, Kp) f16, dst row n = j*4+g  <- src row g*Hout+j
__global__ void conv_w(const float* __restrict__ src, f16* __restrict__ dst,
                       int Hout, int Ksrc, int Kp){
    int n = blockIdx.y;
    int k = blockIdx.x*256 + threadIdx.x;
    if (k >= Kp) return;
    int j = n >> 2, g = n & 3;
    float val = (j < Hout && k < Ksrc) ? src[(g*Hout + j)*Ksrc + k] : 0.f;
    dst[(size_t)n*Kp + k] = (f16)val;
}

// bias'[n] = b_ih[g*Hout+j] + b_hh[g*Hout+j], n=j*4+g, padded 0
__global__ void conv_bias(const float* __restrict__ bi, const float* __restrict__ bh,
                          float* __restrict__ dst, int Hout, int Np){
    int n = blockIdx.x*256 + threadIdx.x;
    if (n >= Np) return;
    int j = n >> 2, g = n & 3;
    dst[n] = (j < Hout) ? (bi[g*Hout + j] + bh[g*Hout + j]) : 0.f;
}

// ---------------- GEMM: C(M,N) = A(M,Kp) * B(N,Kp)^T + bias ----------------
// SC=0: C fp32 row-major stride Nst.  SC=1: scatter out[b][v][t], A rows m=b*128+t.
template<int SC>
__global__ __launch_bounds__(256) void gemm16(
    const f16* __restrict__ A, const f16* __restrict__ B,
    const float* __restrict__ bias, float* __restrict__ C,
    int Kp, int Nst)
{
    __shared__ __align__(16) f16 lA[128*32];
    __shared__ __align__(16) f16 lB[128*32];
    const int lane = threadIdx.x & 63;
    const int wid  = threadIdx.x >> 6;
    const int m0 = blockIdx.y * 128, n0 = blockIdx.x * 128;
    f32x4 acc[4][4] = {};
    const int sr = threadIdx.x >> 2;            // staging row 0..63
    const int sc = (threadIdx.x & 3) * 8;       // staging col
    for (int k0 = 0; k0 < Kp; k0 += 32) {
        __syncthreads();
        *(f16x8*)&lA[ sr      *32 + sc] = *(const f16x8*)&A[(size_t)(m0 + sr     )*Kp + k0 + sc];
        *(f16x8*)&lA[(sr + 64)*32 + sc] = *(const f16x8*)&A[(size_t)(m0 + sr + 64)*Kp + k0 + sc];
        *(f16x8*)&lB[ sr      *32 + sc] = *(const f16x8*)&B[(size_t)(n0 + sr     )*Kp + k0 + sc];
        *(f16x8*)&lB[(sr + 64)*32 + sc] = *(const f16x8*)&B[(size_t)(n0 + sr + 64)*Kp + k0 + sc];
        __syncthreads();
        const int wr = (wid >> 1) * 64, wc = (wid & 1) * 64;
        f16x8 af[4], bf[4];
        #pragma unroll
        for (int i = 0; i < 4; ++i)
            af[i] = *(const f16x8*)&lA[(wr + i*16 + (lane & 15))*32 + (lane >> 4)*8];
        #pragma unroll
        for (int j = 0; j < 4; ++j)
            bf[j] = *(const f16x8*)&lB[(wc + j*16 + (lane & 15))*32 + (lane >> 4)*8];
        #pragma unroll
        for (int i = 0; i < 4; ++i)
            #pragma unroll
            for (int j = 0; j < 4; ++j)
                acc[i][j] = __builtin_amdgcn_mfma_f32_16x16x32_f16(af[i], bf[j], acc[i][j], 0, 0, 0);
    }
    const int wr = (wid >> 1) * 64, wc = (wid & 1) * 64;
    #pragma unroll
    for (int i = 0; i < 4; ++i) {
        #pragma unroll
        for (int j = 0; j < 4; ++j) {
            int gc = n0 + wc + j*16 + (lane & 15);
            float bb = bias[gc];
            #pragma unroll
            for (int r = 0; r < 4; ++r) {
                int gr = m0 + wr + i*16 + (lane >> 4)*4 + r;
                float v = acc[i][j][r] + bb;
                if (SC) C[((size_t)(gr >> 7)*VV + gc)*TT + (gr & 127)] = v;   // out[b][v][t]
                else    C[(size_t)gr*Nst + gc] = v;
            }
        }
    }
}

// ---------------- persistent LSTM recurrence ----------------
// gates(16,N') = h(16,Hp) * W(N',Hp)^T  + pre(t-row)  per step; hand-rolled grid barrier.
// blockIdx.x owns 32 gate columns (8 j's x 4 gates). 4 waves split K.
__global__ __launch_bounds__(256) void lstm_rec(
    const float* __restrict__ pre,   // (2048, Nst) rows t*16+b
    const f16*  __restrict__ W,      // (N', Hp) rows n=j*4+g
    f16* __restrict__ hbuf,          // (16, Hp) zero-initialized
    f16* __restrict__ xsout,         // layer12: (2048,HpOut) rows t*16+b ; layer3: (2048,416) rows b*128+t
    float* __restrict__ hout, float* __restrict__ cout,  // (16,H)
    unsigned* __restrict__ arrive,
    int H, int Hp, int Nst, int HpOut, int layer3)
{
    const int lane = threadIdx.x & 63, kw = threadIdx.x >> 6;
    const int n0 = blockIdx.x * 32;
    const int klen = Hp >> 2, kbase = kw * klen;
    const int nwg = gridDim.x;
    __shared__ float red[4][16][32];
    __shared__ float cst[16][8];
    if (threadIdx.x < 128) cst[threadIdx.x & 15][threadIdx.x >> 4] = 0.f;
    const int arow = lane & 15, aoff = (lane >> 4) * 8;
    const f16* hp  = hbuf + arow * Hp + kbase + aoff;
    const f16* wp0 = W + (size_t)(n0 + arow) * Hp + kbase + aoff;
    const f16* wp1 = wp0 + (size_t)16 * Hp;

    for (int t = 0; t < TT; ++t) {
        f32x4 acc0 = {0.f,0.f,0.f,0.f}, acc1 = {0.f,0.f,0.f,0.f};
        for (int kk = 0; kk < klen; kk += 32) {
            f16x8 av = *(const f16x8*)(hp + kk);
            acc0 = __builtin_amdgcn_mfma_f32_16x16x32_f16(av, *(const f16x8*)(wp0 + kk), acc0, 0, 0, 0);
            acc1 = __builtin_amdgcn_mfma_f32_16x16x32_f16(av, *(const f16x8*)(wp1 + kk), acc1, 0, 0, 0);
        }
        #pragma unroll
        for (int r = 0; r < 4; ++r) {
            red[kw][(lane >> 4)*4 + r][lane & 15]        = acc0[r];
            red[kw][(lane >> 4)*4 + r][16 + (lane & 15)] = acc1[r];
        }
        __syncthreads();
        if (threadIdx.x < 128) {
            const int b = threadIdx.x & 15, jl = threadIdx.x >> 4;  // jl 0..7
            const int nb = jl * 4;
            const f32x4 p4 = *(const f32x4*)(pre + (size_t)(t*16 + b)*Nst + n0 + nb);
            float gi = p4[0] + red[0][b][nb+0] + red[1][b][nb+0] + red[2][b][nb+0] + red[3][b][nb+0];
            float gf = p4[1] + red[0][b][nb+1] + red[1][b][nb+1] + red[2][b][nb+1] + red[3][b][nb+1];
            float gg = p4[2] + red[0][b][nb+2] + red[1][b][nb+2] + red[2][b][nb+2] + red[3][b][nb+2];
            float go = p4[3] + red[0][b][nb+3] + red[1][b][nb+3] + red[2][b][nb+3] + red[3][b][nb+3];
            float c = sigm(gf) * cst[b][jl] + sigm(gi) * tanhf(gg);
            float h = sigm(go) * tanhf(c);
            cst[b][jl] = c;
            const int j = (n0 >> 2) + jl;
            hbuf[b*Hp + j] = (f16)h;
            if (!layer3) xsout[(size_t)(t*16 + b)*HpOut + j] = (f16)h;
            else         xsout[(size_t)(b*TT + t)*416   + j] = (f16)h;
            if (t == TT-1 && j < H) { hout[b*H + j] = h; cout[b*H + j] = c; }
        }
        // grid barrier (monotonic flags, agent scope)
        __threadfence();
        __syncthreads();
        if (threadIdx.x == 0)
            __hip_atomic_store(&arrive[blockIdx.x * 16], (unsigned)(t + 1),
                               __ATOMIC_RELEASE, __HIP_MEMORY_SCOPE_AGENT);
        for (int w = threadIdx.x; w < nwg; w += 256) {
            while (__hip_atomic_load(&arrive[w * 16], __ATOMIC_ACQUIRE,
                                     __HIP_MEMORY_SCOPE_AGENT) < (unsigned)(t + 1))
                __builtin_amdgcn_s_sleep(1);
        }
        __syncthreads();
    }
}

// ---------------- host ----------------
extern "C" void kernel_launch(void* const* d_in, const int* in_sizes, int n_in,
                              void* d_out, int out_size, void* d_ws, size_t ws_size,
                              hipStream_t stream)
{
    const float* emb  = (const float*)d_in[0];
    const float* Wih1 = (const float*)d_in[1];
    const float* Whh1 = (const float*)d_in[2];
    const float* bih1 = (const float*)d_in[3];
    const float* bhh1 = (const float*)d_in[4];
    const float* Wih2 = (const float*)d_in[5];
    const float* Whh2 = (const float*)d_in[6];
    const float* bih2 = (const float*)d_in[7];
    const float* bhh2 = (const float*)d_in[8];
    const float* Wih3 = (const float*)d_in[9];
    const float* Whh3 = (const float*)d_in[10];
    const float* bih3 = (const float*)d_in[11];
    const float* bhh3 = (const float*)d_in[12];
    const float* linb = (const float*)d_in[13];
    const int*   x    = (const int*)d_in[14];
    float* out = (float*)d_out;
    char*  ws  = (char*)d_ws;

    // zero region: barrier flags + h-state buffers
    const size_t ARR1 = 0, ARR2 = 10240, ARR3 = 20480;
    const size_t H1BF = 30720, H2BF = 67584, H3BF = 104448;
    const size_t ZEND = 120832;
    size_t off = ZEND;
    auto alloc = [&](size_t bytes){ size_t r = off; off += (bytes + 255) & ~(size_t)255; return r; };
    const size_t EMBBF = alloc((size_t)VV*416*2);
    const size_t XS0   = alloc((size_t)MM*416*2);
    const size_t XS12  = alloc((size_t)MM*1152*2);
    const size_t XS3   = alloc((size_t)MM*416*2);
    const size_t WIH   = alloc((size_t)4608*1152*2);
    const size_t WHH   = alloc((size_t)4608*1152*2);
    const size_t BIAS  = alloc((size_t)4608*4);

    f16* emb_bf = (f16*)(ws + EMBBF);
    f16* xs0    = (f16*)(ws + XS0);
    f16* xs12   = (f16*)(ws + XS12);
    f16* xs3    = (f16*)(ws + XS3);
    f16* wih    = (f16*)(ws + WIH);
    f16* whh    = (f16*)(ws + WHH);
    float* bias = (float*)(ws + BIAS);
    unsigned* arr1 = (unsigned*)(ws + ARR1);
    unsigned* arr2 = (unsigned*)(ws + ARR2);
    unsigned* arr3 = (unsigned*)(ws + ARR3);
    f16* h1bf = (f16*)(ws + H1BF);
    f16* h2bf = (f16*)(ws + H2BF);
    f16* h3bf = (f16*)(ws + H3BF);

    float* pre = out;                 // reuse out region as pre scratch (37.7MB < 262MB)
    float* H1O = out + 65536000;  float* H2O = H1O + 18400;  float* H3O = H2O + 18400;
    float* C1O = H3O + 6400;      float* C2O = C1O + 18400;  float* C3O = C2O + 18400;

    hipMemsetAsync(d_ws, 0, ZEND, stream);

    conv_emb    <<<dim3(2, VV),   256, 0, stream>>>(emb, emb_bf);
    embed_gather<<<dim3(2, MM),   256, 0, stream>>>(emb, x, xs0);

    // layer 1
    conv_w   <<<dim3(2, 4608), 256, 0, stream>>>(Wih1, wih, HH, EE, 416);
    conv_bias<<<dim3(18),      256, 0, stream>>>(bih1, bhh1, bias, HH, 4608);
    gemm16<0><<<dim3(36, 16),  256, 0, stream>>>(xs0, wih, bias, pre, 416, 4608);
    conv_w   <<<dim3(5, 4608), 256, 0, stream>>>(Whh1, whh, HH, HH, 1152);
    lstm_rec <<<dim3(144),     256, 0, stream>>>(pre, whh, h1bf, xs12, H1O, C1O, arr1,
                                                 HH, 1152, 4608, 1152, 0);
    // layer 2
    conv_w   <<<dim3(5, 4608), 256, 0, stream>>>(Wih2, wih, HH, HH, 1152);
    conv_bias<<<dim3(18),      256, 0, stream>>>(bih2, bhh2, bias, HH, 4608);
    gemm16<0><<<dim3(36, 16),  256, 0, stream>>>(xs12, wih, bias, pre, 1152, 4608);
    conv_w   <<<dim3(5, 4608), 256, 0, stream>>>(Whh2, whh, HH, HH, 1152);
    lstm_rec <<<dim3(144),     256, 0, stream>>>(pre, whh, h2bf, xs12, H2O, C2O, arr2,
                                                 HH, 1152, 4608, 1152, 0);
    // layer 3
    conv_w   <<<dim3(5, 1664), 256, 0, stream>>>(Wih3, wih, EE, HH, 1152);
    conv_bias<<<dim3(7),       256, 0, stream>>>(bih3, bhh3, bias, EE, 1664);
    gemm16<0><<<dim3(13, 16),  256, 0, stream>>>(xs12, wih, bias, pre, 1152, 1664);
    conv_w   <<<dim3(2, 1664), 256, 0, stream>>>(Whh3, whh, EE, EE, 512);
    lstm_rec <<<dim3(52),      256, 0, stream>>>(pre, whh, h3bf, xs3, H3O, C3O, arr3,
                                                 EE, 512, 1664, 416, 1);
    // tied-weight logits with fused transpose to (B,V,T)
    gemm16<1><<<dim3(250, 16), 256, 0, stream>>>(xs3, emb_bf, linb, out, 416, 0);
}

// Round 2
// 4541.672 us; speedup vs baseline: 1.7677x; 1.7677x over previous
//
#include <hip/hip_runtime.h>

typedef _Float16 f16;
typedef _Float16 f16x8 __attribute__((ext_vector_type(8)));
typedef float f32x4 __attribute__((ext_vector_type(4)));

// dims
#define BB 16
#define TT 128
#define VV 32000
#define EE 400
#define HH 1150
#define MM 2048   // T*B rows

__device__ __forceinline__ float sigm(float x){ return 1.f/(1.f + __expf(-x)); }
__device__ __forceinline__ float ftanh(float x){ return 2.f/(1.f + __expf(-2.f*x)) - 1.f; }

// ---------------- conversion kernels ----------------

__global__ void conv_emb(const float* __restrict__ src, f16* __restrict__ dst){
    int v = blockIdx.y;
    int k = blockIdx.x*256 + threadIdx.x;
    if (k >= 416) return;
    float val = (k < EE) ? src[v*EE + k] : 0.f;
    dst[v*416 + k] = (f16)val;
}

__global__ void embed_gather(const float* __restrict__ emb, const int* __restrict__ x,
                             f16* __restrict__ dst){
    int m = blockIdx.y;            // t*16+b
    int k = blockIdx.x*256 + threadIdx.x;
    if (k >= 416) return;
    int t = m >> 4, b = m & 15;
    int row = x[b*TT + t];
    float val = (k < EE) ? emb[row*EE + k] : 0.f;
    dst[m*416 + k] = (f16)val;
}

// W (4*Hout, Ksrc) f32 -> dst (Np, Kp) f16, dst row n = j*4+g  <- src row g*Hout+j
__global__ void conv_w(const float* __restrict__ src, f16* __restrict__ dst,
                       int Hout, int Ksrc, int Kp){
    int n = blockIdx.y;
    int k = blockIdx.x*256 + threadIdx.x;
    if (k >= Kp) return;
    int j = n >> 2, g = n & 3;
    float val = (j < Hout && k < Ksrc) ? src[(g*Hout + j)*Ksrc + k] : 0.f;
    dst[(size_t)n*Kp + k] = (f16)val;
}

__global__ void conv_bias(const float* __restrict__ bi, const float* __restrict__ bh,
                          float* __restrict__ dst, int Hout, int Np){
    int n = blockIdx.x*256 + threadIdx.x;
    if (n >= Np) return;
    int j = n >> 2, g = n & 3;
    dst[n] = (j < Hout) ? (bi[g*Hout + j] + bh[g*Hout + j]) : 0.f;
}

// ---------------- GEMM: C(M,N) = A(M,Kp) * B(N,Kp)^T + bias ----------------
template<int SC>
__global__ __launch_bounds__(256) void gemm16(
    const f16* __restrict__ A, const f16* __restrict__ B,
    const float* __restrict__ bias, float* __restrict__ C,
    int Kp, int Nst)
{
    __shared__ __align__(16) f16 lA[128*32];
    __shared__ __align__(16) f16 lB[128*32];
    const int lane = threadIdx.x & 63;
    const int wid  = threadIdx.x >> 6;
    const int m0 = blockIdx.y * 128, n0 = blockIdx.x * 128;
    f32x4 acc[4][4] = {};
    const int sr = threadIdx.x >> 2;
    const int sc = (threadIdx.x & 3) * 8;
    for (int k0 = 0; k0 < Kp; k0 += 32) {
        __syncthreads();
        *(f16x8*)&lA[ sr      *32 + sc] = *(const f16x8*)&A[(size_t)(m0 + sr     )*Kp + k0 + sc];
        *(f16x8*)&lA[(sr + 64)*32 + sc] = *(const f16x8*)&A[(size_t)(m0 + sr + 64)*Kp + k0 + sc];
        *(f16x8*)&lB[ sr      *32 + sc] = *(const f16x8*)&B[(size_t)(n0 + sr     )*Kp + k0 + sc];
        *(f16x8*)&lB[(sr + 64)*32 + sc] = *(const f16x8*)&B[(size_t)(n0 + sr + 64)*Kp + k0 + sc];
        __syncthreads();
        const int wr = (wid >> 1) * 64, wc = (wid & 1) * 64;
        f16x8 af[4], bf[4];
        #pragma unroll
        for (int i = 0; i < 4; ++i)
            af[i] = *(const f16x8*)&lA[(wr + i*16 + (lane & 15))*32 + (lane >> 4)*8];
        #pragma unroll
        for (int j = 0; j < 4; ++j)
            bf[j] = *(const f16x8*)&lB[(wc + j*16 + (lane & 15))*32 + (lane >> 4)*8];
        #pragma unroll
        for (int i = 0; i < 4; ++i)
            #pragma unroll
            for (int j = 0; j < 4; ++j)
                acc[i][j] = __builtin_amdgcn_mfma_f32_16x16x32_f16(af[i], bf[j], acc[i][j], 0, 0, 0);
    }
    const int wr = (wid >> 1) * 64, wc = (wid & 1) * 64;
    #pragma unroll
    for (int i = 0; i < 4; ++i) {
        #pragma unroll
        for (int j = 0; j < 4; ++j) {
            int gc = n0 + wc + j*16 + (lane & 15);
            float bb = bias[gc];
            #pragma unroll
            for (int r = 0; r < 4; ++r) {
                int gr = m0 + wr + i*16 + (lane >> 4)*4 + r;
                float v = acc[i][j][r] + bb;
                if (SC) C[((size_t)(gr >> 7)*VV + gc)*TT + (gr & 127)] = v;   // out[b][v][t]
                else    C[(size_t)gr*Nst + gc] = v;
            }
        }
    }
}

// ---------------- persistent LSTM recurrence ----------------
// W held in registers (72 VGPRs/lane); h ping-pong double-buffered; one
// release fence + one acquire fence per step; relaxed flag polls.
template<int KITER>   // Hp = KITER*128
__global__ __launch_bounds__(256) void lstm_rec(
    const float* __restrict__ pre,   // (2048, Nst) rows t*16+b
    const f16*  __restrict__ W,      // (N', Hp) rows n=j*4+g
    f16* __restrict__ hbuf0, f16* __restrict__ hbuf1,   // (16, Hp) zeroed
    f16* __restrict__ xsout,
    float* __restrict__ hout, float* __restrict__ cout,  // (16,H)
    unsigned* __restrict__ arrive,
    int H, int Nst, int HpOut, int layer3)
{
    constexpr int Hp = KITER * 128;
    constexpr int klen = Hp >> 2;
    const int lane = threadIdx.x & 63, kw = threadIdx.x >> 6;
    const int n0 = blockIdx.x * 32;
    const int kbase = kw * klen;
    const int nwg = gridDim.x;
    __shared__ float red[4][16][32];
    __shared__ float cst[16][8];
    if (threadIdx.x < 128) cst[threadIdx.x & 15][threadIdx.x >> 4] = 0.f;
    const int arow = lane & 15, aoff = (lane >> 4) * 8;
    const size_t hofs = (size_t)arow * Hp + kbase + aoff;
    const f16* wp0 = W + (size_t)(n0 + arow) * Hp + kbase + aoff;
    const f16* wp1 = wp0 + (size_t)16 * Hp;
    f16x8 w0[KITER], w1[KITER];
    #pragma unroll
    for (int i = 0; i < KITER; ++i) {
        w0[i] = *(const f16x8*)(wp0 + i*32);
        w1[i] = *(const f16x8*)(wp1 + i*32);
    }
    const int b  = threadIdx.x & 15;      // for update half
    const int jl = threadIdx.x >> 4;      // 0..7 when tid<128
    __syncthreads();

    for (int t = 0; t < TT; ++t) {
        const f16* hp = ((t & 1) ? hbuf1 : hbuf0) + hofs;
        f16* hw       =  (t & 1) ? hbuf0 : hbuf1;
        f32x4 p4;
        if (threadIdx.x < 128)
            p4 = *(const f32x4*)(pre + (size_t)(t*16 + b)*Nst + n0 + jl*4);
        f32x4 acc0 = {0.f,0.f,0.f,0.f}, acc1 = {0.f,0.f,0.f,0.f};
        #pragma unroll
        for (int i = 0; i < KITER; ++i) {
            f16x8 av = *(const f16x8*)(hp + i*32);
            acc0 = __builtin_amdgcn_mfma_f32_16x16x32_f16(av, w0[i], acc0, 0, 0, 0);
            acc1 = __builtin_amdgcn_mfma_f32_16x16x32_f16(av, w1[i], acc1, 0, 0, 0);
        }
        #pragma unroll
        for (int r = 0; r < 4; ++r) {
            red[kw][(lane >> 4)*4 + r][lane & 15]        = acc0[r];
            red[kw][(lane >> 4)*4 + r][16 + (lane & 15)] = acc1[r];
        }
        __syncthreads();
        if (threadIdx.x < 128) {
            const int nb = jl * 4;
            float gi = p4[0] + red[0][b][nb+0] + red[1][b][nb+0] + red[2][b][nb+0] + red[3][b][nb+0];
            float gf = p4[1] + red[0][b][nb+1] + red[1][b][nb+1] + red[2][b][nb+1] + red[3][b][nb+1];
            float gg = p4[2] + red[0][b][nb+2] + red[1][b][nb+2] + red[2][b][nb+2] + red[3][b][nb+2];
            float go = p4[3] + red[0][b][nb+3] + red[1][b][nb+3] + red[2][b][nb+3] + red[3][b][nb+3];
            float c = sigm(gf) * cst[b][jl] + sigm(gi) * ftanh(gg);
            float h = sigm(go) * ftanh(c);
            cst[b][jl] = c;
            const int j = (n0 >> 2) + jl;
            hw[b*Hp + j] = (f16)h;
            if (!layer3) xsout[(size_t)(t*16 + b)*HpOut + j] = (f16)h;
            else         xsout[(size_t)(b*TT + t)*416   + j] = (f16)h;
            if (t == TT-1 && j < H) { hout[b*H + j] = h; cout[b*H + j] = c; }
            __builtin_amdgcn_fence(__ATOMIC_RELEASE, "agent");   // waves 0-1: flush h to LLC
        }
        __syncthreads();
        if (threadIdx.x == 0)
            __hip_atomic_store(&arrive[blockIdx.x * 16], (unsigned)(t + 1),
                               __ATOMIC_RELAXED, __HIP_MEMORY_SCOPE_AGENT);
        for (int w = threadIdx.x; w < nwg; w += 256) {
            while (__hip_atomic_load(&arrive[w * 16], __ATOMIC_RELAXED,
                                     __HIP_MEMORY_SCOPE_AGENT) < (unsigned)(t + 1))
                __builtin_amdgcn_s_sleep(1);
        }
        __syncthreads();
        __builtin_amdgcn_fence(__ATOMIC_ACQUIRE, "agent");       // one inv per step
    }
}

// ---------------- host ----------------
extern "C" void kernel_launch(void* const* d_in, const int* in_sizes, int n_in,
                              void* d_out, int out_size, void* d_ws, size_t ws_size,
                              hipStream_t stream)
{
    const float* emb  = (const float*)d_in[0];
    const float* Wih1 = (const float*)d_in[1];
    const float* Whh1 = (const float*)d_in[2];
    const float* bih1 = (const float*)d_in[3];
    const float* bhh1 = (const float*)d_in[4];
    const float* Wih2 = (const float*)d_in[5];
    const float* Whh2 = (const float*)d_in[6];
    const float* bih2 = (const float*)d_in[7];
    const float* bhh2 = (const float*)d_in[8];
    const float* Wih3 = (const float*)d_in[9];
    const float* Whh3 = (const float*)d_in[10];
    const float* bih3 = (const float*)d_in[11];
    const float* bhh3 = (const float*)d_in[12];
    const float* linb = (const float*)d_in[13];
    const int*   x    = (const int*)d_in[14];
    float* out = (float*)d_out;
    char*  ws  = (char*)d_ws;

    // zero region: barrier flags + ping-pong h-state buffers
    const size_t ARR1 = 0, ARR2 = 10240, ARR3 = 20480;
    const size_t H1A = 30720,  H1B = 67584;    // 16*1152*2 = 36864 each
    const size_t H2A = 104448, H2B = 141312;
    const size_t H3A = 178176, H3B = 194560;   // 16*512*2 = 16384 each
    const size_t ZEND = 210944;
    size_t off = ZEND;
    auto alloc = [&](size_t bytes){ size_t r = off; off += (bytes + 255) & ~(size_t)255; return r; };
    const size_t EMBBF = alloc((size_t)VV*416*2);
    const size_t XS0   = alloc((size_t)MM*416*2);
    const size_t XS12  = alloc((size_t)MM*1152*2);
    const size_t XS3   = alloc((size_t)MM*416*2);
    const size_t WIH   = alloc((size_t)4608*1152*2);
    const size_t WHH   = alloc((size_t)4608*1152*2);
    const size_t BIAS  = alloc((size_t)4608*4);

    f16* emb_bf = (f16*)(ws + EMBBF);
    f16* xs0    = (f16*)(ws + XS0);
    f16* xs12   = (f16*)(ws + XS12);
    f16* xs3    = (f16*)(ws + XS3);
    f16* wih    = (f16*)(ws + WIH);
    f16* whh    = (f16*)(ws + WHH);
    float* bias = (float*)(ws + BIAS);
    unsigned* arr1 = (unsigned*)(ws + ARR1);
    unsigned* arr2 = (unsigned*)(ws + ARR2);
    unsigned* arr3 = (unsigned*)(ws + ARR3);

    float* pre = out;                 // reuse out region as pre scratch
    float* H1O = out + 65536000;  float* H2O = H1O + 18400;  float* H3O = H2O + 18400;
    float* C1O = H3O + 6400;      float* C2O = C1O + 18400;  float* C3O = C2O + 18400;

    hipMemsetAsync(d_ws, 0, ZEND, stream);

    conv_emb    <<<dim3(2, VV),   256, 0, stream>>>(emb, emb_bf);
    embed_gather<<<dim3(2, MM),   256, 0, stream>>>(emb, x, xs0);

    // layer 1
    conv_w   <<<dim3(2, 4608), 256, 0, stream>>>(Wih1, wih, HH, EE, 416);
    conv_bias<<<dim3(18),      256, 0, stream>>>(bih1, bhh1, bias, HH, 4608);
    gemm16<0><<<dim3(36, 16),  256, 0, stream>>>(xs0, wih, bias, pre, 416, 4608);
    conv_w   <<<dim3(5, 4608), 256, 0, stream>>>(Whh1, whh, HH, HH, 1152);
    lstm_rec<9><<<dim3(144),   256, 0, stream>>>(pre, whh, (f16*)(ws+H1A), (f16*)(ws+H1B),
                                                 xs12, H1O, C1O, arr1, HH, 4608, 1152, 0);
    // layer 2
    conv_w   <<<dim3(5, 4608), 256, 0, stream>>>(Wih2, wih, HH, HH, 1152);
    conv_bias<<<dim3(18),      256, 0, stream>>>(bih2, bhh2, bias, HH, 4608);
    gemm16<0><<<dim3(36, 16),  256, 0, stream>>>(xs12, wih, bias, pre, 1152, 4608);
    conv_w   <<<dim3(5, 4608), 256, 0, stream>>>(Whh2, whh, HH, HH, 1152);
    lstm_rec<9><<<dim3(144),   256, 0, stream>>>(pre, whh, (f16*)(ws+H2A), (f16*)(ws+H2B),
                                                 xs12, H2O, C2O, arr2, HH, 4608, 1152, 0);
    // layer 3
    conv_w   <<<dim3(5, 1664), 256, 0, stream>>>(Wih3, wih, EE, HH, 1152);
    conv_bias<<<dim3(7),       256, 0, stream>>>(bih3, bhh3, bias, EE, 1664);
    gemm16<0><<<dim3(13, 16),  256, 0, stream>>>(xs12, wih, bias, pre, 1152, 1664);
    conv_w   <<<dim3(2, 1664), 256, 0, stream>>>(Whh3, whh, EE, EE, 512);
    lstm_rec<4><<<dim3(52),    256, 0, stream>>>(pre, whh, (f16*)(ws+H3A), (f16*)(ws+H3B),
                                                 xs3, H3O, C3O, arr3, EE, 1664, 416, 1);
    // tied-weight logits with fused transpose to (B,V,T)
    gemm16<1><<<dim3(250, 16), 256, 0, stream>>>(xs3, emb_bf, linb, out, 416, 0);
}